// Round 4
// baseline (927.850 us; speedup 1.0000x reference)
//
#include <hip/hip_runtime.h>

// 3-layer LSTM stack, fully fused: one wave64 per batch element.
// B=2048, T=512, F=64, H1=16, H2=8, H3=5, OUT=2. fp32 throughout.
// Lane = gate row. L1: rows 0..63 on lanes 0..63 (i/f/g/o strided 16).
// L2: rows 0..31 on lanes 0..31 (strided 8). L3: 20 rows on lane groups
// {0..4,16..20,32..36,48..52} so all gate gathers are shfl_xor 16/32/48
// (8/16/24 for L2). Weights register-resident, pre-scaled by -log2e
// (sigmoid rows) / -2log2e (tanh rows): act = fma(rcp(1+exp2(z)), s2, -s1).
// h broadcasts hoisted once per update (readlane -> SGPR, constant-indexed
// arrays -> stay in SGPRs), shared by next layer and next timestep.
// x rows: forced VECTOR loads (divergent-0 index) hitting L1 warmed by a
// 3-rows-ahead per-lane prefetch; prefetch keep-alive is read 2 iterations
// after issue (pfA/pfB static rotation) so no steady-state vmcnt stall.

#define T_STEPS 512
#define F_IN    64
#define BATCH   2048

typedef float v2f __attribute__((ext_vector_type(2)));
typedef float v4f __attribute__((ext_vector_type(4)));

__device__ __forceinline__ v2f mkv2(float a, float b) { v2f r; r.x = a; r.y = b; return r; }

__device__ __forceinline__ float fexp2(float x) {
#if __has_builtin(__builtin_amdgcn_exp2f)
    return __builtin_amdgcn_exp2f(x);
#else
    return exp2f(x);
#endif
}
__device__ __forceinline__ float frcp(float x) {
#if __has_builtin(__builtin_amdgcn_rcpf)
    return __builtin_amdgcn_rcpf(x);
#else
    return 1.0f / x;
#endif
}

// broadcast lane l of v to all lanes (v_readlane -> SGPR result)
__device__ __forceinline__ float bl(float v, int l) {
    return __int_as_float(__builtin_amdgcn_readlane(__float_as_int(v), l));
}

// tanh(x) = 2/(1+exp2(-2*log2e*x)) - 1
__device__ __forceinline__ float ftanh(float x) {
    float e = fexp2(x * -2.885390081777927f);
    return fmaf(frcp(1.0f + e), 2.0f, -1.0f);
}

__launch_bounds__(64, 2)   // 2 waves/EU (grid supplies 8 blocks/CU); VGPR cap 256
__global__ void lstm3_fused(const float* __restrict__ x,
                            const float* __restrict__ Wih1, const float* __restrict__ Whh1, const float* __restrict__ b1,
                            const float* __restrict__ Wih2, const float* __restrict__ Whh2, const float* __restrict__ b2,
                            const float* __restrict__ Wih3, const float* __restrict__ Whh3, const float* __restrict__ b3,
                            const float* __restrict__ Wout, const float* __restrict__ bout,
                            float* __restrict__ out)
{
    const int lane = threadIdx.x & 63;
    const int b    = blockIdx.x;          // batch element; wave-uniform
    // divergent-valued 0: forces x-row reads onto the vector-memory path
    const int di   = (int)__builtin_amdgcn_mbcnt_lo(0u, 0u);

    const float LOG2E = 1.4426950408889634f;

    // ---- per-lane activation selectors (tanh on 'g' gate rows) ----
    const bool t1 = (lane >= 32 && lane < 48);          // L1 g rows 32..47
    const float mk1 = t1 ? -2.0f * LOG2E : -LOG2E;
    const float s2_1 = t1 ? 2.0f : 1.0f;
    const float ms1_1 = t1 ? -1.0f : 0.0f;

    const int l2 = lane & 31;                           // L2 row (dup high half)
    const bool t2 = (l2 >= 16 && l2 < 24);              // L2 g rows 16..23
    const float mk2s = t2 ? -2.0f * LOG2E : -LOG2E;
    const float s2_2 = t2 ? 2.0f : 1.0f;
    const float ms1_2 = t2 ? -1.0f : 0.0f;

    const int c15 = lane & 15;                          // L3: 4 lane-groups of 5
    const int l3 = (c15 < 5) ? (5 * (lane >> 4) + c15) : 0;
    const bool t3 = (lane >= 32 && lane < 37);          // L3 g rows 10..14
    const float mk3 = t3 ? -2.0f * LOG2E : -LOG2E;
    const float s2_3 = t3 ? 2.0f : 1.0f;
    const float ms1_3 = t3 ? -1.0f : 0.0f;

    // ---------------- weight load (one-time, tiny, L2-cached) ----------------
    v2f wih1[32]; float whh1[16]; float b1r;
    {
        const float* r  = Wih1 + lane * F_IN;
        #pragma unroll
        for (int f = 0; f < 32; ++f) wih1[f] = mkv2(r[2*f] * mk1, r[2*f+1] * mk1);
        const float* rh = Whh1 + lane * 16;
        #pragma unroll
        for (int j = 0; j < 16; ++j) whh1[j] = rh[j] * mk1;
        b1r = b1[lane] * mk1;
    }
    float wih2[16], whh2[8], b2r;
    {
        const float* r  = Wih2 + l2 * 16;
        #pragma unroll
        for (int j = 0; j < 16; ++j) wih2[j] = r[j] * mk2s;
        const float* rh = Whh2 + l2 * 8;
        #pragma unroll
        for (int j = 0; j < 8; ++j) whh2[j] = rh[j] * mk2s;
        b2r = b2[l2] * mk2s;
    }
    float wih3[8], whh3[5], b3r;
    {
        const float* r  = Wih3 + l3 * 8;
        #pragma unroll
        for (int j = 0; j < 8; ++j) wih3[j] = r[j] * mk3;
        const float* rh = Whh3 + l3 * 5;
        #pragma unroll
        for (int j = 0; j < 5; ++j) whh3[j] = rh[j] * mk3;
        b3r = b3[l3] * mk3;
    }
    const int lo = lane & 1;
    float wo[5], bor;
    {
        #pragma unroll
        for (int j = 0; j < 5; ++j) wo[j] = Wout[lo * 5 + j];
        bor = bout[lo];
    }

    // ---------------- state ----------------
    float h1 = 0.0f, c1 = 0.0f;
    float h2 = 0.0f, c2 = 0.0f;
    float h3 = 0.0f, c3 = 0.0f;
    float hb1[16]; float hb2[8]; float hb3[5];   // hoisted broadcasts (SGPR)
    #pragma unroll
    for (int j = 0; j < 16; ++j) hb1[j] = 0.0f;
    #pragma unroll
    for (int j = 0; j < 8; ++j)  hb2[j] = 0.0f;
    #pragma unroll
    for (int j = 0; j < 5; ++j)  hb3[j] = 0.0f;

    const float* __restrict__ xb = x + (size_t)b * (T_STEPS * F_IN);

    float pfA = 0.0f, pfB = 0.0f;   // prefetch slots, static 2-rotation

    auto step = [&](int t, float& pfSlot) {
        // keep-alive for the prefetch issued 2 iterations ago (vmcnt long drained),
        // then issue prefetch for row t+3 into the same slot.
        asm volatile("" :: "v"(pfSlot));
        {
            int tn = (t + 3 < T_STEPS) ? t + 3 : T_STEPS - 1;
            pfSlot = xb[tn * F_IN + lane];
        }

        const v4f* __restrict__ xt4 = (const v4f*)(xb + t * F_IN + di);  // vector path

        // ======== Layer 1: 64 gate rows, one per lane ========
        v2f a0 = mkv2(b1r, 0.0f), a1 = mkv2(0.0f, 0.0f), a2 = mkv2(0.0f, 0.0f), a3 = mkv2(0.0f, 0.0f);
        #pragma unroll
        for (int q = 0; q < 16; q += 2) {
            v4f xA = xt4[q], xB = xt4[q + 1];
            a0 += xA.lo * wih1[2*q + 0];
            a1 += xA.hi * wih1[2*q + 1];
            a2 += xB.lo * wih1[2*q + 2];
            a3 += xB.hi * wih1[2*q + 3];
        }
        v2f sv = (a0 + a1) + (a2 + a3);
        float za = sv.x, zb = sv.y, zc = 0.0f, zd = 0.0f;
        #pragma unroll
        for (int j = 0; j < 16; j += 4) {
            za = fmaf(hb1[j + 0], whh1[j + 0], za);
            zb = fmaf(hb1[j + 1], whh1[j + 1], zb);
            zc = fmaf(hb1[j + 2], whh1[j + 2], zc);
            zd = fmaf(hb1[j + 3], whh1[j + 3], zd);
        }
        {
            float z = (za + zb) + (zc + zd);             // pre-scaled by mk1
            float act = fmaf(frcp(1.0f + fexp2(z)), s2_1, ms1_1);
            float fv = __shfl_xor(act, 16, 64);
            float gv = __shfl_xor(act, 32, 64);
            float ov = __shfl_xor(act, 48, 64);
            c1 = fmaf(fv, c1, act * gv);                 // valid on lanes 0..15
            h1 = ov * ftanh(c1);
        }
        #pragma unroll
        for (int j = 0; j < 16; ++j) hb1[j] = bl(h1, j); // new h1 -> SGPRs

        // ======== Layer 2: 32 gate rows on lanes 0..31 ========
        float g0 = b2r, g1 = 0.0f, g2 = 0.0f, g3 = 0.0f;
        #pragma unroll
        for (int j = 0; j < 16; j += 4) {
            g0 = fmaf(hb1[j + 0], wih2[j + 0], g0);
            g1 = fmaf(hb1[j + 1], wih2[j + 1], g1);
            g2 = fmaf(hb1[j + 2], wih2[j + 2], g2);
            g3 = fmaf(hb1[j + 3], wih2[j + 3], g3);
        }
        #pragma unroll
        for (int j = 0; j < 8; j += 4) {
            g0 = fmaf(hb2[j + 0], whh2[j + 0], g0);
            g1 = fmaf(hb2[j + 1], whh2[j + 1], g1);
            g2 = fmaf(hb2[j + 2], whh2[j + 2], g2);
            g3 = fmaf(hb2[j + 3], whh2[j + 3], g3);
        }
        {
            float z = (g0 + g1) + (g2 + g3);
            float act = fmaf(frcp(1.0f + fexp2(z)), s2_2, ms1_2);
            float fv = __shfl_xor(act, 8, 64);
            float gv = __shfl_xor(act, 16, 64);
            float ov = __shfl_xor(act, 24, 64);
            c2 = fmaf(fv, c2, act * gv);                 // valid on lanes 0..7
            h2 = ov * ftanh(c2);
        }
        #pragma unroll
        for (int j = 0; j < 8; ++j) hb2[j] = bl(h2, j);  // new h2 -> SGPRs

        // ======== Layer 3: 20 rows on lane groups {0..4,16..20,32..36,48..52} ========
        float q0 = b3r, q1 = 0.0f, q2 = 0.0f, q3 = 0.0f;
        #pragma unroll
        for (int j = 0; j < 8; j += 4) {
            q0 = fmaf(hb2[j + 0], wih3[j + 0], q0);
            q1 = fmaf(hb2[j + 1], wih3[j + 1], q1);
            q2 = fmaf(hb2[j + 2], wih3[j + 2], q2);
            q3 = fmaf(hb2[j + 3], wih3[j + 3], q3);
        }
        q0 = fmaf(hb3[0], whh3[0], q0);
        q1 = fmaf(hb3[1], whh3[1], q1);
        q2 = fmaf(hb3[2], whh3[2], q2);
        q3 = fmaf(hb3[3], whh3[3], q3);
        q0 = fmaf(hb3[4], whh3[4], q0);
        {
            float z = (q0 + q1) + (q2 + q3);
            float act = fmaf(frcp(1.0f + fexp2(z)), s2_3, ms1_3);
            float fv = __shfl_xor(act, 16, 64);
            float gv = __shfl_xor(act, 32, 64);
            float ov = __shfl_xor(act, 48, 64);
            c3 = fmaf(fv, c3, act * gv);                 // valid on lanes 0..4
            h3 = ov * ftanh(c3);
        }
        #pragma unroll
        for (int j = 0; j < 5; ++j) hb3[j] = bl(h3, j);  // new h3 -> SGPRs
    };

    #pragma unroll 1
    for (int t = 0; t < T_STEPS; t += 2) {
        step(t + 0, pfA);
        step(t + 1, pfB);
    }

    // ======== final linear: out[b,k] = sum_j h3[j]*Wout[k,j] + bout[k] ========
    float o = bor;
    #pragma unroll
    for (int j = 0; j < 5; ++j) o = fmaf(hb3[j], wo[j], o);
    if (lane < 2) out[(size_t)b * 2 + lane] = o;
}

extern "C" void kernel_launch(void* const* d_in, const int* in_sizes, int n_in,
                              void* d_out, int out_size, void* d_ws, size_t ws_size,
                              hipStream_t stream) {
    const float* x    = (const float*)d_in[0];
    const float* Wih1 = (const float*)d_in[1];
    const float* Whh1 = (const float*)d_in[2];
    const float* b1   = (const float*)d_in[3];
    const float* Wih2 = (const float*)d_in[4];
    const float* Whh2 = (const float*)d_in[5];
    const float* b2   = (const float*)d_in[6];
    const float* Wih3 = (const float*)d_in[7];
    const float* Whh3 = (const float*)d_in[8];
    const float* b3   = (const float*)d_in[9];
    const float* Wout = (const float*)d_in[10];
    const float* bout = (const float*)d_in[11];
    float* out = (float*)d_out;

    dim3 grid(BATCH), block(64);
    lstm3_fused<<<grid, block, 0, stream>>>(x, Wih1, Whh1, b1, Wih2, Whh2, b2,
                                            Wih3, Whh3, b3, Wout, bout, out);
}

// Round 8
// 792.607 us; speedup vs baseline: 1.1706x; 1.1706x over previous
//
#include <hip/hip_runtime.h>

// 3-layer LSTM stack, fully fused: one wave64 per batch element.
// B=2048, T=512, F=64, H1=16, H2=8, H3=5, OUT=2. fp32 throughout.
// Lane = gate row. L1: rows 0..63 on lanes 0..63 (i/f/g/o strided 16).
// L2: rows 0..31 on lanes 0..31 (strided 8). L3: 20 rows on lane groups
// {0..4,16..20,32..36,48..52} so all gate gathers are shfl_xor 16/32/48
// (8/16/24 for L2). Weights register-resident, pre-scaled by -log2e
// (sigmoid rows) / -2log2e (tanh rows): act = fma(rcp(1+exp2(z)), s2, -s1).
// h broadcasts hoisted once per update (readlane -> SGPR), shared by next
// layer and next timestep.
// x row: ONE coalesced per-lane dword load per step (lane f holds x[t][f]),
// software-pipelined 2 steps ahead (xvA/xvB static rotation, zero stall),
// then x[f] broadcast via v_readlane (SGPR operand feeds FMA directly).
// R4 lesson: 16 uniform dwordx4 loads/step serialized on VGPR pressure
// (load->wait->use at ~200cyc each ~= the whole 3170cyc/step).

#define T_STEPS 512
#define F_IN    64
#define BATCH   2048

__device__ __forceinline__ float fexp2(float x) {
#if __has_builtin(__builtin_amdgcn_exp2f)
    return __builtin_amdgcn_exp2f(x);
#else
    return exp2f(x);
#endif
}
__device__ __forceinline__ float frcp(float x) {
#if __has_builtin(__builtin_amdgcn_rcpf)
    return __builtin_amdgcn_rcpf(x);
#else
    return 1.0f / x;
#endif
}

// broadcast lane l of v to all lanes (v_readlane -> SGPR result)
__device__ __forceinline__ float bl(float v, int l) {
    return __int_as_float(__builtin_amdgcn_readlane(__float_as_int(v), l));
}

// tanh(x) = 2/(1+exp2(-2*log2e*x)) - 1
__device__ __forceinline__ float ftanh(float x) {
    float e = fexp2(x * -2.885390081777927f);
    return fmaf(frcp(1.0f + e), 2.0f, -1.0f);
}

__launch_bounds__(64, 2)   // 2 waves/EU (grid supplies 8 blocks/CU); VGPR cap 256
__global__ void lstm3_fused(const float* __restrict__ x,
                            const float* __restrict__ Wih1, const float* __restrict__ Whh1, const float* __restrict__ b1,
                            const float* __restrict__ Wih2, const float* __restrict__ Whh2, const float* __restrict__ b2,
                            const float* __restrict__ Wih3, const float* __restrict__ Whh3, const float* __restrict__ b3,
                            const float* __restrict__ Wout, const float* __restrict__ bout,
                            float* __restrict__ out)
{
    const int lane = threadIdx.x & 63;
    const int b    = blockIdx.x;          // batch element; wave-uniform

    const float LOG2E = 1.4426950408889634f;

    // ---- per-lane activation selectors (tanh on 'g' gate rows) ----
    const bool t1 = (lane >= 32 && lane < 48);          // L1 g rows 32..47
    const float mk1 = t1 ? -2.0f * LOG2E : -LOG2E;
    const float s2_1 = t1 ? 2.0f : 1.0f;
    const float ms1_1 = t1 ? -1.0f : 0.0f;

    const int l2 = lane & 31;                           // L2 row (dup high half)
    const bool t2 = (l2 >= 16 && l2 < 24);              // L2 g rows 16..23
    const float mk2s = t2 ? -2.0f * LOG2E : -LOG2E;
    const float s2_2 = t2 ? 2.0f : 1.0f;
    const float ms1_2 = t2 ? -1.0f : 0.0f;

    const int c15 = lane & 15;                          // L3: 4 lane-groups of 5
    const int l3 = (c15 < 5) ? (5 * (lane >> 4) + c15) : 0;
    const bool t3 = (lane >= 32 && lane < 37);          // L3 g rows 10..14
    const float mk3 = t3 ? -2.0f * LOG2E : -LOG2E;
    const float s2_3 = t3 ? 2.0f : 1.0f;
    const float ms1_3 = t3 ? -1.0f : 0.0f;

    // ---------------- weight load (one-time, tiny, L2-cached) ----------------
    float wih1[F_IN], whh1[16], b1r;
    {
        const float* r  = Wih1 + lane * F_IN;
        #pragma unroll
        for (int f = 0; f < F_IN; ++f) wih1[f] = r[f] * mk1;
        const float* rh = Whh1 + lane * 16;
        #pragma unroll
        for (int j = 0; j < 16; ++j) whh1[j] = rh[j] * mk1;
        b1r = b1[lane] * mk1;
    }
    float wih2[16], whh2[8], b2r;
    {
        const float* r  = Wih2 + l2 * 16;
        #pragma unroll
        for (int j = 0; j < 16; ++j) wih2[j] = r[j] * mk2s;
        const float* rh = Whh2 + l2 * 8;
        #pragma unroll
        for (int j = 0; j < 8; ++j) whh2[j] = rh[j] * mk2s;
        b2r = b2[l2] * mk2s;
    }
    float wih3[8], whh3[5], b3r;
    {
        const float* r  = Wih3 + l3 * 8;
        #pragma unroll
        for (int j = 0; j < 8; ++j) wih3[j] = r[j] * mk3;
        const float* rh = Whh3 + l3 * 5;
        #pragma unroll
        for (int j = 0; j < 5; ++j) whh3[j] = rh[j] * mk3;
        b3r = b3[l3] * mk3;
    }
    const int lo = lane & 1;
    float wo[5], bor;
    {
        #pragma unroll
        for (int j = 0; j < 5; ++j) wo[j] = Wout[lo * 5 + j];
        bor = bout[lo];
    }

    // ---------------- state ----------------
    float h1 = 0.0f, c1 = 0.0f;
    float h2 = 0.0f, c2 = 0.0f;
    float h3 = 0.0f, c3 = 0.0f;
    float hb1[16]; float hb2[8]; float hb3[5];   // hoisted broadcasts (SGPR)
    #pragma unroll
    for (int j = 0; j < 16; ++j) hb1[j] = 0.0f;
    #pragma unroll
    for (int j = 0; j < 8; ++j)  hb2[j] = 0.0f;
    #pragma unroll
    for (int j = 0; j < 5; ++j)  hb3[j] = 0.0f;

    const float* __restrict__ xb = x + (size_t)b * (T_STEPS * F_IN);

    // 2-deep software pipeline: xvA/xvB hold rows t and t+1 (lane f = x[t][f]).
    float xvA = xb[0 * F_IN + lane];
    float xvB = xb[1 * F_IN + lane];

    auto step = [&](int t, float& slot) {
        const float xv = slot;                  // row t, loaded 2 steps ago
        {
            int tn = (t + 2 < T_STEPS) ? t + 2 : T_STEPS - 1;
            slot = xb[tn * F_IN + lane];        // coalesced 256B; consumed at t+2
        }

        // ======== Layer 1: 64 gate rows, one per lane ========
        // x[f] broadcast from lane f via readlane (SGPR), 4 independent chains.
        float za = b1r, zb = 0.0f, zc = 0.0f, zd = 0.0f;
        #pragma unroll
        for (int f = 0; f < F_IN; f += 4) {
            za = fmaf(bl(xv, f + 0), wih1[f + 0], za);
            zb = fmaf(bl(xv, f + 1), wih1[f + 1], zb);
            zc = fmaf(bl(xv, f + 2), wih1[f + 2], zc);
            zd = fmaf(bl(xv, f + 3), wih1[f + 3], zd);
        }
        #pragma unroll
        for (int j = 0; j < 16; j += 4) {
            za = fmaf(hb1[j + 0], whh1[j + 0], za);
            zb = fmaf(hb1[j + 1], whh1[j + 1], zb);
            zc = fmaf(hb1[j + 2], whh1[j + 2], zc);
            zd = fmaf(hb1[j + 3], whh1[j + 3], zd);
        }
        {
            float z = (za + zb) + (zc + zd);             // pre-scaled by mk1
            float act = fmaf(frcp(1.0f + fexp2(z)), s2_1, ms1_1);
            float fv = __shfl_xor(act, 16, 64);
            float gv = __shfl_xor(act, 32, 64);
            float ov = __shfl_xor(act, 48, 64);
            c1 = fmaf(fv, c1, act * gv);                 // valid on lanes 0..15
            h1 = ov * ftanh(c1);
        }
        #pragma unroll
        for (int j = 0; j < 16; ++j) hb1[j] = bl(h1, j); // new h1 -> SGPRs

        // ======== Layer 2: 32 gate rows on lanes 0..31 ========
        float g0 = b2r, g1 = 0.0f, g2 = 0.0f, g3 = 0.0f;
        #pragma unroll
        for (int j = 0; j < 16; j += 4) {
            g0 = fmaf(hb1[j + 0], wih2[j + 0], g0);
            g1 = fmaf(hb1[j + 1], wih2[j + 1], g1);
            g2 = fmaf(hb1[j + 2], wih2[j + 2], g2);
            g3 = fmaf(hb1[j + 3], wih2[j + 3], g3);
        }
        #pragma unroll
        for (int j = 0; j < 8; j += 4) {
            g0 = fmaf(hb2[j + 0], whh2[j + 0], g0);
            g1 = fmaf(hb2[j + 1], whh2[j + 1], g1);
            g2 = fmaf(hb2[j + 2], whh2[j + 2], g2);
            g3 = fmaf(hb2[j + 3], whh2[j + 3], g3);
        }
        {
            float z = (g0 + g1) + (g2 + g3);
            float act = fmaf(frcp(1.0f + fexp2(z)), s2_2, ms1_2);
            float fv = __shfl_xor(act, 8, 64);
            float gv = __shfl_xor(act, 16, 64);
            float ov = __shfl_xor(act, 24, 64);
            c2 = fmaf(fv, c2, act * gv);                 // valid on lanes 0..7
            h2 = ov * ftanh(c2);
        }
        #pragma unroll
        for (int j = 0; j < 8; ++j) hb2[j] = bl(h2, j);  // new h2 -> SGPRs

        // ======== Layer 3: 20 rows on lane groups {0..4,16..20,32..36,48..52} ========
        float q0 = b3r, q1 = 0.0f, q2 = 0.0f, q3 = 0.0f;
        #pragma unroll
        for (int j = 0; j < 8; j += 4) {
            q0 = fmaf(hb2[j + 0], wih3[j + 0], q0);
            q1 = fmaf(hb2[j + 1], wih3[j + 1], q1);
            q2 = fmaf(hb2[j + 2], wih3[j + 2], q2);
            q3 = fmaf(hb2[j + 3], wih3[j + 3], q3);
        }
        q0 = fmaf(hb3[0], whh3[0], q0);
        q1 = fmaf(hb3[1], whh3[1], q1);
        q2 = fmaf(hb3[2], whh3[2], q2);
        q3 = fmaf(hb3[3], whh3[3], q3);
        q0 = fmaf(hb3[4], whh3[4], q0);
        {
            float z = (q0 + q1) + (q2 + q3);
            float act = fmaf(frcp(1.0f + fexp2(z)), s2_3, ms1_3);
            float fv = __shfl_xor(act, 16, 64);
            float gv = __shfl_xor(act, 32, 64);
            float ov = __shfl_xor(act, 48, 64);
            c3 = fmaf(fv, c3, act * gv);                 // valid on lanes 0..4
            h3 = ov * ftanh(c3);
        }
        #pragma unroll
        for (int j = 0; j < 5; ++j) hb3[j] = bl(h3, j);  // new h3 -> SGPRs
    };

    #pragma unroll 1
    for (int t = 0; t < T_STEPS; t += 2) {
        step(t + 0, xvA);
        step(t + 1, xvB);
    }

    // ======== final linear: out[b,k] = sum_j h3[j]*Wout[k,j] + bout[k] ========
    float o = bor;
    #pragma unroll
    for (int j = 0; j < 5; ++j) o = fmaf(hb3[j], wo[j], o);
    if (lane < 2) out[(size_t)b * 2 + lane] = o;
}

extern "C" void kernel_launch(void* const* d_in, const int* in_sizes, int n_in,
                              void* d_out, int out_size, void* d_ws, size_t ws_size,
                              hipStream_t stream) {
    const float* x    = (const float*)d_in[0];
    const float* Wih1 = (const float*)d_in[1];
    const float* Whh1 = (const float*)d_in[2];
    const float* b1   = (const float*)d_in[3];
    const float* Wih2 = (const float*)d_in[4];
    const float* Whh2 = (const float*)d_in[5];
    const float* b2   = (const float*)d_in[6];
    const float* Wih3 = (const float*)d_in[7];
    const float* Whh3 = (const float*)d_in[8];
    const float* b3   = (const float*)d_in[9];
    const float* Wout = (const float*)d_in[10];
    const float* bout = (const float*)d_in[11];
    float* out = (float*)d_out;

    dim3 grid(BATCH), block(64);
    lstm3_fused<<<grid, block, 0, stream>>>(x, Wih1, Whh1, b1, Wih2, Whh2, b2,
                                            Wih3, Whh3, b3, Wout, bout, out);
}